// Round 14
// baseline (596.948 us; speedup 1.0000x reference)
//
#include <hip/hip_runtime.h>
#include <math.h>

typedef __bf16 bf16;
typedef bf16  bf16x8 __attribute__((ext_vector_type(8)));
typedef bf16  bf16x4 __attribute__((ext_vector_type(4)));
typedef bf16  bf16x2 __attribute__((ext_vector_type(2)));
typedef float f32x4  __attribute__((ext_vector_type(4)));

#define BSH2 8        // bucket = 256 nodes
#define PCH  8192     // edges per partition chunk
#define CAP  4608     // LDS record capacity per bucket (mean 4096, 8 sigma margin)

// ---------------- degree / norm precompute ----------------

__global__ void zero_i32(int* __restrict__ p, int n) {
    int i = blockIdx.x * blockDim.x + threadIdx.x;
    if (i < n) p[i] = 0;
}

__global__ void count_deg(const int* __restrict__ dst, int* __restrict__ deg, int E) {
    int i = blockIdx.x * blockDim.x + threadIdx.x;
    int stride = gridDim.x * blockDim.x;
    for (; i < E; i += stride) atomicAdd(&deg[dst[i]], 1);
}

__global__ void finalize_dinv(const int* __restrict__ deg, float* __restrict__ dinv, int n) {
    int i = blockIdx.x * blockDim.x + threadIdx.x;
    if (i < n) dinv[i] = rsqrtf((float)deg[i] + 1.0f);   // +1 self-loop
}

// ---------------- parallel 3-phase exclusive scan (node offsets) ----------------
#define SCHUNK 2048

__global__ __launch_bounds__(256) void scan_p1(const int* __restrict__ deg,
                                               int* __restrict__ bsum, int n) {
    int base = blockIdx.x * SCHUNK;
    int s = 0;
    for (int i = threadIdx.x; i < SCHUNK; i += 256) {
        int idx = base + i;
        s += (idx < n) ? deg[idx] : 0;
    }
    #pragma unroll
    for (int o = 32; o >= 1; o >>= 1) s += __shfl_xor(s, o, 64);
    __shared__ int ws[4];
    if ((threadIdx.x & 63) == 0) ws[threadIdx.x >> 6] = s;
    __syncthreads();
    if (threadIdx.x == 0) bsum[blockIdx.x] = ws[0] + ws[1] + ws[2] + ws[3];
}

__global__ __launch_bounds__(64) void scan_p2(int* __restrict__ bsum,
                                              int* __restrict__ off, int nb, int n) {
    int lane = threadIdx.x;
    __shared__ int carry_s;
    if (lane == 0) carry_s = 0;
    __syncthreads();
    for (int base = 0; base < nb; base += 64) {
        int i = base + lane;
        int v = (i < nb) ? bsum[i] : 0;
        int x = v;
        #pragma unroll
        for (int o = 1; o < 64; o <<= 1) {
            int t = __shfl_up(x, o, 64);
            if (lane >= o) x += t;
        }
        int carry = carry_s;
        if (i < nb) bsum[i] = carry + x - v;   // exclusive
        int total = __shfl(x, 63, 64);
        __syncthreads();
        if (lane == 0) carry_s = carry + total;
        __syncthreads();
    }
    if (lane == 0) off[n] = carry_s;
}

__global__ __launch_bounds__(256) void scan_p3(const int* __restrict__ deg,
                                               const int* __restrict__ bsum,
                                               int* __restrict__ off,
                                               int* __restrict__ cursor, int n) {
    int base = blockIdx.x * SCHUNK + (int)threadIdx.x * 8;
    int v[8]; int s = 0;
    #pragma unroll
    for (int j = 0; j < 8; j++) {
        int idx = base + j;
        v[j] = (idx < n) ? deg[idx] : 0;
        s += v[j];
    }
    int lane = threadIdx.x & 63, wv = threadIdx.x >> 6;
    int x = s;
    #pragma unroll
    for (int o = 1; o < 64; o <<= 1) {
        int t = __shfl_up(x, o, 64);
        if (lane >= o) x += t;
    }
    __shared__ int wsum[4];
    if (lane == 63) wsum[wv] = x;
    __syncthreads();
    int wbase = 0;
    #pragma unroll
    for (int w = 0; w < 4; w++) if (w < wv) wbase += wsum[w];
    int tbase = bsum[blockIdx.x] + wbase + x - s;   // exclusive prefix for this thread
    #pragma unroll
    for (int j = 0; j < 8; j++) {
        int idx = base + j;
        if (idx < n) { off[idx] = tbase; cursor[idx] = 0; tbase += v[j]; }
    }
}

// ---------------- pass 1: partition edges by dst bucket (dst>>8), coalesced runs ----------------

__global__ __launch_bounds__(256) void partition_edges(
    const int* __restrict__ src, const int* __restrict__ dst,
    const int* __restrict__ off, int* __restrict__ bcur,
    uint2* __restrict__ ebuf, int E, int n, int nbk)
{
    __shared__ int lhist[512];
    __shared__ int lbase[512];
    __shared__ int lcur[512];
    __shared__ int gbase[512];
    __shared__ int csum[8];
    __shared__ unsigned short stage[PCH];   // 16 KB

    const int tid = threadIdx.x, lane = tid & 63, wv = tid >> 6;

    for (int base = blockIdx.x * PCH; base < E; base += gridDim.x * PCH) {
        const int cnt = min(PCH, E - base);

        for (int b = tid; b < 512; b += 256) lhist[b] = 0;
        __syncthreads();
        for (int i = tid; i < cnt; i += 256)
            atomicAdd(&lhist[dst[base + i] >> BSH2], 1);
        __syncthreads();
        for (int c = wv; c < 8; c += 4) {
            int idx = c * 64 + lane;
            int v = lhist[idx], x = v;
            #pragma unroll
            for (int o = 1; o < 64; o <<= 1) {
                int t = __shfl_up(x, o, 64);
                if (lane >= o) x += t;
            }
            lbase[idx] = x - v;
            if (lane == 63) csum[c] = x;
        }
        __syncthreads();
        if (tid == 0) {
            int acc = 0;
            #pragma unroll
            for (int c = 0; c < 8; c++) { int t = csum[c]; csum[c] = acc; acc += t; }
        }
        __syncthreads();
        for (int c = wv; c < 8; c += 4) {
            int idx = c * 64 + lane;
            lbase[idx] += csum[c];
            lcur[idx] = lbase[idx];
        }
        __syncthreads();
        for (int i = tid; i < cnt; i += 256) {
            int b = dst[base + i] >> BSH2;
            int p = atomicAdd(&lcur[b], 1);
            stage[p] = (unsigned short)i;
        }
        __syncthreads();
        for (int b = tid; b < nbk; b += 256) {
            int cb = lbase[b + 1] - lbase[b];
            if (cb > 0) gbase[b] = off[b << BSH2] + atomicAdd(&bcur[b], cb);
        }
        __syncthreads();
        for (int k = tid; k < cnt; k += 256) {
            int i = base + (int)stage[k];
            int s = src[i], d = dst[i];
            int b = d >> BSH2;
            ebuf[gbase[b] + (k - lbase[b])] = make_uint2((unsigned)s, (unsigned)d);
        }
        __syncthreads();
    }
}

// ---------------- pass 2: per-bucket LDS counting sort -> coalesced erec write ----------------

__global__ __launch_bounds__(256) void fill_sort(
    const uint2* __restrict__ ebuf, const int* __restrict__ off,
    const float* __restrict__ dinv, int* __restrict__ gcur,
    uint2* __restrict__ erec, int n, int nbk)
{
    __shared__ int  lcur[256];
    __shared__ uint2 lrec[CAP];   // 36 KB

    for (int b = blockIdx.x; b < nbk; b += gridDim.x) {
        const int n0 = b << BSH2;
        const int n1 = min(n0 + 256, n);
        const int e0 = off[n0], e1 = off[n1];
        const int cnt = e1 - e0;
        if (threadIdx.x < (unsigned)(n1 - n0))
            lcur[threadIdx.x] = off[n0 + threadIdx.x] - e0;
        __syncthreads();
        if (cnt <= CAP) {
            for (int i = threadIdx.x; i < cnt; i += 256) {
                uint2 q = ebuf[e0 + i];
                int s = (int)q.x, d = (int)q.y;
                int p = atomicAdd(&lcur[d - n0], 1);
                lrec[p] = make_uint2(q.x, (unsigned)__float_as_uint(dinv[s] * dinv[d]));
            }
            __syncthreads();
            for (int i = threadIdx.x; i < cnt; i += 256)
                erec[e0 + i] = lrec[i];
        } else {
            for (int i = threadIdx.x; i < cnt; i += 256) {
                uint2 q = ebuf[e0 + i];
                int s = (int)q.x, d = (int)q.y;
                int p = off[d] + atomicAdd(&gcur[d], 1);
                erec[p] = make_uint2(q.x, (unsigned)__float_as_uint(dinv[s] * dinv[d]));
            }
        }
        __syncthreads();
    }
}

// ---------------- fp32 -> split bf16 (hi/lo) ----------------

__global__ __launch_bounds__(256) void split_relu(
    const float* __restrict__ in, bf16* __restrict__ hi, bf16* __restrict__ lo,
    long long n4, int do_relu)
{
    long long i = (long long)blockIdx.x * blockDim.x + threadIdx.x;
    long long stride = (long long)gridDim.x * blockDim.x;
    for (; i < n4; i += stride) {
        float4 v = *(const float4*)(in + i * 4);
        if (do_relu) {
            v.x = fmaxf(v.x, 0.f); v.y = fmaxf(v.y, 0.f);
            v.z = fmaxf(v.z, 0.f); v.w = fmaxf(v.w, 0.f);
        }
        bf16x4 h, l;
        h[0] = (bf16)v.x; l[0] = (bf16)(v.x - (float)h[0]);
        h[1] = (bf16)v.y; l[1] = (bf16)(v.y - (float)h[1]);
        h[2] = (bf16)v.z; l[2] = (bf16)(v.z - (float)h[2]);
        h[3] = (bf16)v.w; l[3] = (bf16)(v.w - (float)h[3]);
        *(bf16x4*)(hi + i * 4) = h;
        *(bf16x4*)(lo + i * 4) = l;
    }
}

// ---------------- MFMA GEMM (swapped operands): C^T = W^T @ A^T ----------------

__global__ __launch_bounds__(256) void gemm_mfma(
    const bf16* __restrict__ ahi, const bf16* __restrict__ alo,
    const float* __restrict__ W, const float* __restrict__ bias,
    bf16* __restrict__ ohi, bf16* __restrict__ olo, int n_rows, int relu_out)
{
    const int lane = threadIdx.x & 63;
    const int wv   = threadIdx.x >> 6;
    const int col0 = wv * 32;
    const int l15  = lane & 15;
    const int lg   = lane >> 4;

    bf16x8 whi[2][4], wlo[2][4];
    #pragma unroll
    for (int t = 0; t < 2; t++) {
        int c = col0 + 16 * t + l15;
        #pragma unroll
        for (int ks = 0; ks < 4; ks++) {
            #pragma unroll
            for (int j = 0; j < 8; j++) {
                float wvv = W[(ks * 32 + lg * 8 + j) * 128 + c];
                bf16 h = (bf16)wvv;
                whi[t][ks][j] = h;
                wlo[t][ks][j] = (bf16)(wvv - (float)h);
            }
        }
    }

    const int nrt = n_rows >> 4;
    for (int rt = blockIdx.x; rt < nrt; rt += gridDim.x) {
        const int row = rt * 16 + l15;
        const bf16* pah = ahi + (size_t)row * 128 + lg * 8;
        const bf16* pal = alo + (size_t)row * 128 + lg * 8;
        bf16x8 Ah[4], Al[4];
        #pragma unroll
        for (int ks = 0; ks < 4; ks++) {
            Ah[ks] = *(const bf16x8*)(pah + ks * 32);
            Al[ks] = *(const bf16x8*)(pal + ks * 32);
        }
        #pragma unroll
        for (int t = 0; t < 2; t++) {
            f32x4 acc = {0.f, 0.f, 0.f, 0.f};
            #pragma unroll
            for (int ks = 0; ks < 4; ks++) {
                acc = __builtin_amdgcn_mfma_f32_16x16x32_bf16(whi[t][ks], Al[ks], acc, 0, 0, 0);
                acc = __builtin_amdgcn_mfma_f32_16x16x32_bf16(wlo[t][ks], Ah[ks], acc, 0, 0, 0);
                acc = __builtin_amdgcn_mfma_f32_16x16x32_bf16(whi[t][ks], Ah[ks], acc, 0, 0, 0);
            }
            const int c0 = col0 + 16 * t + lg * 4;
            f32x4 bv = {0.f, 0.f, 0.f, 0.f};
            if (bias) bv = *(const f32x4*)(bias + c0);
            bf16x4 h, l;
            #pragma unroll
            for (int r = 0; r < 4; r++) {
                float v = acc[r] + bv[r];
                if (relu_out) v = fmaxf(v, 0.f);
                h[r] = (bf16)v;
                l[r] = (bf16)(v - (float)h[r]);
            }
            size_t base = (size_t)(rt * 16 + l15) * 128 + c0;
            *(bf16x4*)(ohi + base) = h;
            *(bf16x4*)(olo + base) = l;
        }
    }
}

// ---------------- CSR gather aggregation: 2 nodes/wave, 4 feats/lane ----------------
// Lanes 0-31 -> node 2p, lanes 32-63 -> node 2p+1; lane covers feats (lane&31)*4..+3
// via one bf16x4 8B load per edge. One load instruction services 2 edges (one per
// half). Both halves advance together; OOB edges clamp to a valid record, weight 0.

__global__ __launch_bounds__(256) void gather_agg_split(
    const bf16* __restrict__ hhi, const bf16* __restrict__ hlo,
    const uint2* __restrict__ erec, const int* __restrict__ off,
    const float* __restrict__ dinv, const float* __restrict__ bias,
    bf16* __restrict__ ohi, bf16* __restrict__ olo, int n)
{
    const int lane  = threadIdx.x & 63;
    const int l32   = lane & 31;
    const int half  = lane >> 5;
    const int f     = l32 * 4;

    int wid = (blockIdx.x * 256 + threadIdx.x) >> 6;
    int nw  = (gridDim.x * 256) >> 6;
    const int npairs = (n + 1) >> 1;

    const f32x4 bb = *(const f32x4*)(bias + f);

    for (int pair = wid; pair < npairs; pair += nw) {
        int node = pair * 2 + half;
        if (node >= n) node = n - 1;          // dup lane-work, store guarded below
        float sn = dinv[node]; sn *= sn;
        size_t nb = (size_t)node * 128 + f;
        bf16x4 sh = *(const bf16x4*)(hhi + nb);
        bf16x4 sl = *(const bf16x4*)(hlo + nb);
        float a0 = fmaf((float)sh[0] + (float)sl[0], sn, bb[0]);
        float a1 = fmaf((float)sh[1] + (float)sl[1], sn, bb[1]);
        float a2 = fmaf((float)sh[2] + (float)sl[2], sn, bb[2]);
        float a3 = fmaf((float)sh[3] + (float)sl[3], sn, bb[3]);

        const int e0 = off[node], e1 = off[node + 1];
        int e = e0;
        while (__any(e < e1)) {
            #pragma unroll
            for (int j = 0; j < 8; j++) {
                int idx = e + j;
                bool valid = idx < e1;
                if (!valid) idx = (e1 > e0) ? e1 - 1 : e0;   // clamp to a readable slot
                uint2 q = erec[idx];
                float w = valid ? __uint_as_float(q.y) : 0.f;
                bf16x4 r = *(const bf16x4*)(hhi + (size_t)q.x * 128 + f);
                a0 = fmaf((float)r[0], w, a0);
                a1 = fmaf((float)r[1], w, a1);
                a2 = fmaf((float)r[2], w, a2);
                a3 = fmaf((float)r[3], w, a3);
            }
            e += 8;
        }

        a0 = fmaxf(a0, 0.f); a1 = fmaxf(a1, 0.f);
        a2 = fmaxf(a2, 0.f); a3 = fmaxf(a3, 0.f);
        bf16x4 oh, ol;
        oh[0] = (bf16)a0; ol[0] = (bf16)(a0 - (float)oh[0]);
        oh[1] = (bf16)a1; ol[1] = (bf16)(a1 - (float)oh[1]);
        oh[2] = (bf16)a2; ol[2] = (bf16)(a2 - (float)oh[2]);
        oh[3] = (bf16)a3; ol[3] = (bf16)(a3 - (float)oh[3]);
        if (pair * 2 + half < n) {
            *(bf16x4*)(ohi + nb) = oh;
            *(bf16x4*)(olo + nb) = ol;
        }
    }
}

// ---------------- lin2 + log_softmax via MFMA (swapped operands) ----------------

__global__ __launch_bounds__(256) void lin2_mfma_lsm(
    const bf16* __restrict__ hhi, const bf16* __restrict__ hlo,
    const float* __restrict__ W, const float* __restrict__ bias,
    float* __restrict__ out, int n)
{
    const int lane = threadIdx.x & 63;
    const int l15  = lane & 15;
    const int lg   = lane >> 4;

    bf16x8 whi[3][4], wlo[3][4];
    #pragma unroll
    for (int t = 0; t < 3; t++) {
        int c = t * 16 + l15;
        bool valid = c < 40;
        #pragma unroll
        for (int ks = 0; ks < 4; ks++) {
            #pragma unroll
            for (int j = 0; j < 8; j++) {
                float wv = valid ? W[(ks * 32 + lg * 8 + j) * 40 + c] : 0.f;
                bf16 h = (bf16)wv;
                whi[t][ks][j] = h;
                wlo[t][ks][j] = (bf16)(wv - (float)h);
            }
        }
    }
    f32x4 bb[3];
    bool vstore[3];
    #pragma unroll
    for (int t = 0; t < 3; t++) {
        int c0 = t * 16 + lg * 4;
        vstore[t] = (c0 < 40);
        if (vstore[t]) bb[t] = *(const f32x4*)(bias + c0);
        else bb[t] = (f32x4){0.f, 0.f, 0.f, 0.f};
    }

    int wtile = (blockIdx.x * 256 + threadIdx.x) >> 6;
    int nwt   = (gridDim.x * 256) >> 6;
    int ntiles = (n + 15) >> 4;

    for (int rt = wtile; rt < ntiles; rt += nwt) {
        int arow = rt * 16 + l15;
        if (arow >= n) arow = n - 1;
        const bf16* pah = hhi + (size_t)arow * 128 + lg * 8;
        const bf16* pal = hlo + (size_t)arow * 128 + lg * 8;
        bf16x8 Ah[4], Al[4];
        #pragma unroll
        for (int ks = 0; ks < 4; ks++) {
            Ah[ks] = *(const bf16x8*)(pah + ks * 32);
            Al[ks] = *(const bf16x8*)(pal + ks * 32);
        }
        f32x4 acc[3];
        #pragma unroll
        for (int t = 0; t < 3; t++) {
            acc[t] = (f32x4){0.f, 0.f, 0.f, 0.f};
            #pragma unroll
            for (int ks = 0; ks < 4; ks++) {
                acc[t] = __builtin_amdgcn_mfma_f32_16x16x32_bf16(whi[t][ks], Al[ks], acc[t], 0, 0, 0);
                acc[t] = __builtin_amdgcn_mfma_f32_16x16x32_bf16(wlo[t][ks], Ah[ks], acc[t], 0, 0, 0);
                acc[t] = __builtin_amdgcn_mfma_f32_16x16x32_bf16(whi[t][ks], Ah[ks], acc[t], 0, 0, 0);
            }
        }
        float m = -INFINITY;
        #pragma unroll
        for (int t = 0; t < 3; t++) {
            if (vstore[t]) {
                #pragma unroll
                for (int r = 0; r < 4; r++) m = fmaxf(m, acc[t][r] + bb[t][r]);
            }
        }
        m = fmaxf(m, __shfl_xor(m, 16, 64));
        m = fmaxf(m, __shfl_xor(m, 32, 64));
        float s = 0.f;
        #pragma unroll
        for (int t = 0; t < 3; t++) {
            if (vstore[t]) {
                #pragma unroll
                for (int r = 0; r < 4; r++) s += __expf(acc[t][r] + bb[t][r] - m);
            }
        }
        s += __shfl_xor(s, 16, 64);
        s += __shfl_xor(s, 32, 64);
        float ls = __logf(s) + m;

        int node = rt * 16 + l15;
        if (node < n) {
            #pragma unroll
            for (int t = 0; t < 3; t++) {
                if (vstore[t]) {
                    f32x4 o;
                    #pragma unroll
                    for (int r = 0; r < 4; r++) o[r] = acc[t][r] + bb[t][r] - ls;
                    *(f32x4*)(out + (size_t)node * 40 + t * 16 + lg * 4) = o;
                }
            }
        }
    }
}

// ---------------- launch ----------------

static inline size_t align256(size_t x) { return (x + 255) & ~(size_t)255; }

extern "C" void kernel_launch(void* const* d_in, const int* in_sizes, int n_in,
                              void* d_out, int out_size, void* d_ws, size_t ws_size,
                              hipStream_t stream)
{
    const float* x   = (const float*)d_in[0];
    const int*   ei  = (const int*)d_in[1];
    const float* W1  = (const float*)d_in[2];  const float* b1  = (const float*)d_in[3];
    const float* W2  = (const float*)d_in[4];  const float* b2  = (const float*)d_in[5];
    const float* W3  = (const float*)d_in[6];  const float* b3  = (const float*)d_in[7];
    const float* l1w = (const float*)d_in[8];  const float* l1b = (const float*)d_in[9];
    const float* l2w = (const float*)d_in[10]; const float* l2b = (const float*)d_in[11];

    const int N = in_sizes[0] / 128;
    const int E = in_sizes[1] / 2;
    const int* src = ei;
    const int* dst = ei + E;

    char* wsb = (char*)d_ws;
    size_t o = 0;
    int*   deg   = (int*)(wsb + o);   o = align256(o + (size_t)N * 4);        // reused as cursor
    int*   off   = (int*)(wsb + o);   o = align256(o + (size_t)(N + 1) * 4);
    int*   bsum  = (int*)(wsb + o);   o = align256(o + (size_t)4096 * 4);
    int*   bcur  = (int*)(wsb + o);   o = align256(o + (size_t)512 * 4);
    uint2* erec  = (uint2*)(wsb + o); o = align256(o + (size_t)E * 8);
    float* dinv  = (float*)(wsb + o); o = align256(o + (size_t)N * 4);
    bf16*  ahi   = (bf16*)(wsb + o);  o = align256(o + (size_t)N * 128 * 2);
    bf16*  alo   = (bf16*)(wsb + o);  o = align256(o + (size_t)N * 128 * 2);
    bf16*  hhi   = (bf16*)(wsb + o);  o = align256(o + (size_t)N * 128 * 2);
    bf16*  hlo   = (bf16*)(wsb + o);  o = align256(o + (size_t)N * 128 * 2);

    uint2* ebuf = (uint2*)hhi;   // dead until gemm1; 12.8MB < 25.6MB region

    float* outp = (float*)d_out;
    const int nb   = (N + SCHUNK - 1) / SCHUNK;
    const int nbk  = (N + 255) >> BSH2;                 // 391 buckets
    const int npart = (E + PCH - 1) / PCH;              // 196 chunks

    // ---- CSR build: count, scan, partition, LDS counting sort ----
    zero_i32<<<(N + 255) / 256, 256, 0, stream>>>(deg, N);
    zero_i32<<<2, 256, 0, stream>>>(bcur, 512);
    count_deg<<<2048, 256, 0, stream>>>(dst, deg, E);
    finalize_dinv<<<(N + 255) / 256, 256, 0, stream>>>(deg, dinv, N);
    scan_p1<<<nb, 256, 0, stream>>>(deg, bsum, N);
    scan_p2<<<1, 64, 0, stream>>>(bsum, off, nb, N);
    scan_p3<<<nb, 256, 0, stream>>>(deg, bsum, off, deg /*cursor*/, N);
    partition_edges<<<npart, 256, 0, stream>>>(src, dst, off, bcur, ebuf, E, N, nbk);
    fill_sort<<<nbk, 256, 0, stream>>>(ebuf, off, dinv, deg /*cursor*/, erec, N, nbk);

    // ---- split x ----
    split_relu<<<4096, 256, 0, stream>>>(x, ahi, alo, (long long)N * 32, 0);

    // ---- layer 1 ----
    gemm_mfma<<<1024, 256, 0, stream>>>(ahi, alo, W1, nullptr, hhi, hlo, N, 0);
    gather_agg_split<<<4096, 256, 0, stream>>>(hhi, hlo, erec, off, dinv, b1, ahi, alo, N);

    // ---- layer 2 ----
    gemm_mfma<<<1024, 256, 0, stream>>>(ahi, alo, W2, nullptr, hhi, hlo, N, 0);
    gather_agg_split<<<4096, 256, 0, stream>>>(hhi, hlo, erec, off, dinv, b2, ahi, alo, N);

    // ---- layer 3 ----
    gemm_mfma<<<1024, 256, 0, stream>>>(ahi, alo, W3, nullptr, hhi, hlo, N, 0);
    gather_agg_split<<<4096, 256, 0, stream>>>(hhi, hlo, erec, off, dinv, b3, ahi, alo, N);

    // ---- lin1 (+bias+relu) -> split bf16 ----
    gemm_mfma<<<1024, 256, 0, stream>>>(ahi, alo, l1w, l1b, hhi, hlo, N, 1);

    // ---- lin2 + log_softmax (MFMA, swapped) ----
    lin2_mfma_lsm<<<512, 256, 0, stream>>>(hhi, hlo, l2w, l2b, outp, N);
}

// Round 15
// 503.494 us; speedup vs baseline: 1.1856x; 1.1856x over previous
//
#include <hip/hip_runtime.h>
#include <math.h>

typedef __bf16 bf16;
typedef bf16  bf16x8 __attribute__((ext_vector_type(8)));
typedef bf16  bf16x4 __attribute__((ext_vector_type(4)));
typedef bf16  bf16x2 __attribute__((ext_vector_type(2)));
typedef float f32x4  __attribute__((ext_vector_type(4)));

#define BSH2 8        // bucket = 256 nodes
#define PCH  8192     // edges per partition chunk
#define CAP  4608     // LDS record capacity per bucket (mean 4096, 8 sigma margin)

// ---------------- degree / norm precompute ----------------

__global__ void zero_i32(int* __restrict__ p, int n) {
    int i = blockIdx.x * blockDim.x + threadIdx.x;
    if (i < n) p[i] = 0;
}

__global__ void count_deg(const int* __restrict__ dst, int* __restrict__ deg, int E) {
    int i = blockIdx.x * blockDim.x + threadIdx.x;
    int stride = gridDim.x * blockDim.x;
    for (; i < E; i += stride) atomicAdd(&deg[dst[i]], 1);
}

__global__ void finalize_dinv(const int* __restrict__ deg, float* __restrict__ dinv, int n) {
    int i = blockIdx.x * blockDim.x + threadIdx.x;
    if (i < n) dinv[i] = rsqrtf((float)deg[i] + 1.0f);   // +1 self-loop
}

// ---------------- parallel 3-phase exclusive scan (node offsets) ----------------
#define SCHUNK 2048

__global__ __launch_bounds__(256) void scan_p1(const int* __restrict__ deg,
                                               int* __restrict__ bsum, int n) {
    int base = blockIdx.x * SCHUNK;
    int s = 0;
    for (int i = threadIdx.x; i < SCHUNK; i += 256) {
        int idx = base + i;
        s += (idx < n) ? deg[idx] : 0;
    }
    #pragma unroll
    for (int o = 32; o >= 1; o >>= 1) s += __shfl_xor(s, o, 64);
    __shared__ int ws[4];
    if ((threadIdx.x & 63) == 0) ws[threadIdx.x >> 6] = s;
    __syncthreads();
    if (threadIdx.x == 0) bsum[blockIdx.x] = ws[0] + ws[1] + ws[2] + ws[3];
}

__global__ __launch_bounds__(64) void scan_p2(int* __restrict__ bsum,
                                              int* __restrict__ off, int nb, int n) {
    int lane = threadIdx.x;
    __shared__ int carry_s;
    if (lane == 0) carry_s = 0;
    __syncthreads();
    for (int base = 0; base < nb; base += 64) {
        int i = base + lane;
        int v = (i < nb) ? bsum[i] : 0;
        int x = v;
        #pragma unroll
        for (int o = 1; o < 64; o <<= 1) {
            int t = __shfl_up(x, o, 64);
            if (lane >= o) x += t;
        }
        int carry = carry_s;
        if (i < nb) bsum[i] = carry + x - v;   // exclusive
        int total = __shfl(x, 63, 64);
        __syncthreads();
        if (lane == 0) carry_s = carry + total;
        __syncthreads();
    }
    if (lane == 0) off[n] = carry_s;
}

__global__ __launch_bounds__(256) void scan_p3(const int* __restrict__ deg,
                                               const int* __restrict__ bsum,
                                               int* __restrict__ off,
                                               int* __restrict__ cursor, int n) {
    int base = blockIdx.x * SCHUNK + (int)threadIdx.x * 8;
    int v[8]; int s = 0;
    #pragma unroll
    for (int j = 0; j < 8; j++) {
        int idx = base + j;
        v[j] = (idx < n) ? deg[idx] : 0;
        s += v[j];
    }
    int lane = threadIdx.x & 63, wv = threadIdx.x >> 6;
    int x = s;
    #pragma unroll
    for (int o = 1; o < 64; o <<= 1) {
        int t = __shfl_up(x, o, 64);
        if (lane >= o) x += t;
    }
    __shared__ int wsum[4];
    if (lane == 63) wsum[wv] = x;
    __syncthreads();
    int wbase = 0;
    #pragma unroll
    for (int w = 0; w < 4; w++) if (w < wv) wbase += wsum[w];
    int tbase = bsum[blockIdx.x] + wbase + x - s;   // exclusive prefix for this thread
    #pragma unroll
    for (int j = 0; j < 8; j++) {
        int idx = base + j;
        if (idx < n) { off[idx] = tbase; cursor[idx] = 0; tbase += v[j]; }
    }
}

// ---------------- pass 1: partition edges by dst bucket (dst>>8), coalesced runs ----------------

__global__ __launch_bounds__(256) void partition_edges(
    const int* __restrict__ src, const int* __restrict__ dst,
    const int* __restrict__ off, int* __restrict__ bcur,
    uint2* __restrict__ ebuf, int E, int n, int nbk)
{
    __shared__ int lhist[512];
    __shared__ int lbase[512];
    __shared__ int lcur[512];
    __shared__ int gbase[512];
    __shared__ int csum[8];
    __shared__ unsigned short stage[PCH];   // 16 KB

    const int tid = threadIdx.x, lane = tid & 63, wv = tid >> 6;

    for (int base = blockIdx.x * PCH; base < E; base += gridDim.x * PCH) {
        const int cnt = min(PCH, E - base);

        for (int b = tid; b < 512; b += 256) lhist[b] = 0;
        __syncthreads();
        for (int i = tid; i < cnt; i += 256)
            atomicAdd(&lhist[dst[base + i] >> BSH2], 1);
        __syncthreads();
        for (int c = wv; c < 8; c += 4) {
            int idx = c * 64 + lane;
            int v = lhist[idx], x = v;
            #pragma unroll
            for (int o = 1; o < 64; o <<= 1) {
                int t = __shfl_up(x, o, 64);
                if (lane >= o) x += t;
            }
            lbase[idx] = x - v;
            if (lane == 63) csum[c] = x;
        }
        __syncthreads();
        if (tid == 0) {
            int acc = 0;
            #pragma unroll
            for (int c = 0; c < 8; c++) { int t = csum[c]; csum[c] = acc; acc += t; }
        }
        __syncthreads();
        for (int c = wv; c < 8; c += 4) {
            int idx = c * 64 + lane;
            lbase[idx] += csum[c];
            lcur[idx] = lbase[idx];
        }
        __syncthreads();
        for (int i = tid; i < cnt; i += 256) {
            int b = dst[base + i] >> BSH2;
            int p = atomicAdd(&lcur[b], 1);
            stage[p] = (unsigned short)i;
        }
        __syncthreads();
        for (int b = tid; b < nbk; b += 256) {
            int cb = lbase[b + 1] - lbase[b];
            if (cb > 0) gbase[b] = off[b << BSH2] + atomicAdd(&bcur[b], cb);
        }
        __syncthreads();
        for (int k = tid; k < cnt; k += 256) {
            int i = base + (int)stage[k];
            int s = src[i], d = dst[i];
            int b = d >> BSH2;
            ebuf[gbase[b] + (k - lbase[b])] = make_uint2((unsigned)s, (unsigned)d);
        }
        __syncthreads();
    }
}

// ---------------- pass 2: per-bucket LDS counting sort -> coalesced erec write ----------------

__global__ __launch_bounds__(256) void fill_sort(
    const uint2* __restrict__ ebuf, const int* __restrict__ off,
    const float* __restrict__ dinv, int* __restrict__ gcur,
    uint2* __restrict__ erec, int n, int nbk)
{
    __shared__ int  lcur[256];
    __shared__ uint2 lrec[CAP];   // 36 KB

    for (int b = blockIdx.x; b < nbk; b += gridDim.x) {
        const int n0 = b << BSH2;
        const int n1 = min(n0 + 256, n);
        const int e0 = off[n0], e1 = off[n1];
        const int cnt = e1 - e0;
        if (threadIdx.x < (unsigned)(n1 - n0))
            lcur[threadIdx.x] = off[n0 + threadIdx.x] - e0;
        __syncthreads();
        if (cnt <= CAP) {
            for (int i = threadIdx.x; i < cnt; i += 256) {
                uint2 q = ebuf[e0 + i];
                int s = (int)q.x, d = (int)q.y;
                int p = atomicAdd(&lcur[d - n0], 1);
                lrec[p] = make_uint2(q.x, (unsigned)__float_as_uint(dinv[s] * dinv[d]));
            }
            __syncthreads();
            for (int i = threadIdx.x; i < cnt; i += 256)
                erec[e0 + i] = lrec[i];
        } else {
            for (int i = threadIdx.x; i < cnt; i += 256) {
                uint2 q = ebuf[e0 + i];
                int s = (int)q.x, d = (int)q.y;
                int p = off[d] + atomicAdd(&gcur[d], 1);
                erec[p] = make_uint2(q.x, (unsigned)__float_as_uint(dinv[s] * dinv[d]));
            }
        }
        __syncthreads();
    }
}

// ---------------- MFMA GEMM (swapped operands): C^T = W^T @ A^T ----------------
// bf16 hi/lo input version (layers 2,3, lin1).

__global__ __launch_bounds__(256) void gemm_mfma(
    const bf16* __restrict__ ahi, const bf16* __restrict__ alo,
    const float* __restrict__ W, const float* __restrict__ bias,
    bf16* __restrict__ ohi, bf16* __restrict__ olo, int n_rows, int relu_out)
{
    const int lane = threadIdx.x & 63;
    const int wv   = threadIdx.x >> 6;
    const int col0 = wv * 32;
    const int l15  = lane & 15;
    const int lg   = lane >> 4;

    bf16x8 whi[2][4], wlo[2][4];
    #pragma unroll
    for (int t = 0; t < 2; t++) {
        int c = col0 + 16 * t + l15;
        #pragma unroll
        for (int ks = 0; ks < 4; ks++) {
            #pragma unroll
            for (int j = 0; j < 8; j++) {
                float wvv = W[(ks * 32 + lg * 8 + j) * 128 + c];
                bf16 h = (bf16)wvv;
                whi[t][ks][j] = h;
                wlo[t][ks][j] = (bf16)(wvv - (float)h);
            }
        }
    }

    const int nrt = n_rows >> 4;
    for (int rt = blockIdx.x; rt < nrt; rt += gridDim.x) {
        const int row = rt * 16 + l15;
        const bf16* pah = ahi + (size_t)row * 128 + lg * 8;
        const bf16* pal = alo + (size_t)row * 128 + lg * 8;
        bf16x8 Ah[4], Al[4];
        #pragma unroll
        for (int ks = 0; ks < 4; ks++) {
            Ah[ks] = *(const bf16x8*)(pah + ks * 32);
            Al[ks] = *(const bf16x8*)(pal + ks * 32);
        }
        #pragma unroll
        for (int t = 0; t < 2; t++) {
            f32x4 acc = {0.f, 0.f, 0.f, 0.f};
            #pragma unroll
            for (int ks = 0; ks < 4; ks++) {
                acc = __builtin_amdgcn_mfma_f32_16x16x32_bf16(whi[t][ks], Al[ks], acc, 0, 0, 0);
                acc = __builtin_amdgcn_mfma_f32_16x16x32_bf16(wlo[t][ks], Ah[ks], acc, 0, 0, 0);
                acc = __builtin_amdgcn_mfma_f32_16x16x32_bf16(whi[t][ks], Ah[ks], acc, 0, 0, 0);
            }
            const int c0 = col0 + 16 * t + lg * 4;
            f32x4 bv = {0.f, 0.f, 0.f, 0.f};
            if (bias) bv = *(const f32x4*)(bias + c0);
            bf16x4 h, l;
            #pragma unroll
            for (int r = 0; r < 4; r++) {
                float v = acc[r] + bv[r];
                if (relu_out) v = fmaxf(v, 0.f);
                h[r] = (bf16)v;
                l[r] = (bf16)(v - (float)h[r]);
            }
            size_t base = (size_t)(rt * 16 + l15) * 128 + c0;
            *(bf16x4*)(ohi + base) = h;
            *(bf16x4*)(olo + base) = l;
        }
    }
}

// ---------------- MFMA GEMM, fp32 input (layer 1): split x in-register ----------------
// Reads X fp32 directly (same bytes as ahi+alo would be) -> deletes split_relu pass.

__global__ __launch_bounds__(256) void gemm_mfma_x(
    const float* __restrict__ X, const float* __restrict__ W,
    bf16* __restrict__ ohi, bf16* __restrict__ olo, int n_rows)
{
    const int lane = threadIdx.x & 63;
    const int wv   = threadIdx.x >> 6;
    const int col0 = wv * 32;
    const int l15  = lane & 15;
    const int lg   = lane >> 4;

    bf16x8 whi[2][4], wlo[2][4];
    #pragma unroll
    for (int t = 0; t < 2; t++) {
        int c = col0 + 16 * t + l15;
        #pragma unroll
        for (int ks = 0; ks < 4; ks++) {
            #pragma unroll
            for (int j = 0; j < 8; j++) {
                float wvv = W[(ks * 32 + lg * 8 + j) * 128 + c];
                bf16 h = (bf16)wvv;
                whi[t][ks][j] = h;
                wlo[t][ks][j] = (bf16)(wvv - (float)h);
            }
        }
    }

    const int nrt = n_rows >> 4;
    for (int rt = blockIdx.x; rt < nrt; rt += gridDim.x) {
        const int row = rt * 16 + l15;
        const float* px = X + (size_t)row * 128 + lg * 8;
        bf16x8 Ah[4], Al[4];
        #pragma unroll
        for (int ks = 0; ks < 4; ks++) {
            float4 v0 = *(const float4*)(px + ks * 32);
            float4 v1 = *(const float4*)(px + ks * 32 + 4);
            float vv[8] = {v0.x, v0.y, v0.z, v0.w, v1.x, v1.y, v1.z, v1.w};
            #pragma unroll
            for (int j = 0; j < 8; j++) {
                bf16 h = (bf16)vv[j];
                Ah[ks][j] = h;
                Al[ks][j] = (bf16)(vv[j] - (float)h);
            }
        }
        #pragma unroll
        for (int t = 0; t < 2; t++) {
            f32x4 acc = {0.f, 0.f, 0.f, 0.f};
            #pragma unroll
            for (int ks = 0; ks < 4; ks++) {
                acc = __builtin_amdgcn_mfma_f32_16x16x32_bf16(whi[t][ks], Al[ks], acc, 0, 0, 0);
                acc = __builtin_amdgcn_mfma_f32_16x16x32_bf16(wlo[t][ks], Ah[ks], acc, 0, 0, 0);
                acc = __builtin_amdgcn_mfma_f32_16x16x32_bf16(whi[t][ks], Ah[ks], acc, 0, 0, 0);
            }
            const int c0 = col0 + 16 * t + lg * 4;
            bf16x4 h, l;
            #pragma unroll
            for (int r = 0; r < 4; r++) {
                float v = acc[r];
                h[r] = (bf16)v;
                l[r] = (bf16)(v - (float)h[r]);
            }
            size_t base = (size_t)(rt * 16 + l15) * 128 + c0;
            *(bf16x4*)(ohi + base) = h;
            *(bf16x4*)(olo + base) = l;
        }
    }
}

// ---------------- CSR gather aggregation (bf16 messages) + relu + split epilogue ----------------
// R13 version: 1 node/wave, lane covers feats {2l,2l+1}, 8/4/1 edge unroll.

__global__ __launch_bounds__(256) void gather_agg_split(
    const bf16* __restrict__ hhi, const bf16* __restrict__ hlo,
    const uint2* __restrict__ erec, const int* __restrict__ off,
    const float* __restrict__ dinv, const float* __restrict__ bias,
    bf16* __restrict__ ohi, bf16* __restrict__ olo, int n)
{
    int lane = threadIdx.x & 63;
    int wid  = (blockIdx.x * 256 + threadIdx.x) >> 6;
    int nw   = (gridDim.x * 256) >> 6;

    const int f = 2 * lane;
    float bb0 = bias[f], bb1 = bias[f + 1];

    for (int node = wid; node < n; node += nw) {
        float sn = dinv[node]; sn *= sn;
        size_t nb = (size_t)node * 128 + f;
        bf16x2 sh = *(const bf16x2*)(hhi + nb);
        bf16x2 sl = *(const bf16x2*)(hlo + nb);
        float a0 = fmaf((float)sh[0] + (float)sl[0], sn, bb0);
        float a1 = fmaf((float)sh[1] + (float)sl[1], sn, bb1);

        int e0 = off[node], e1 = off[node + 1];
        int e = e0;
        for (; e + 8 <= e1; e += 8) {
            uint2 q[8];
            #pragma unroll
            for (int j = 0; j < 8; j++) q[j] = erec[e + j];
            bf16x2 r[8];
            #pragma unroll
            for (int j = 0; j < 8; j++)
                r[j] = *(const bf16x2*)(hhi + (size_t)q[j].x * 128 + f);
            #pragma unroll
            for (int j = 0; j < 8; j++) {
                float w = __uint_as_float(q[j].y);
                a0 = fmaf((float)r[j][0], w, a0);
                a1 = fmaf((float)r[j][1], w, a1);
            }
        }
        for (; e + 4 <= e1; e += 4) {
            uint2 q[4];
            #pragma unroll
            for (int j = 0; j < 4; j++) q[j] = erec[e + j];
            bf16x2 r[4];
            #pragma unroll
            for (int j = 0; j < 4; j++)
                r[j] = *(const bf16x2*)(hhi + (size_t)q[j].x * 128 + f);
            #pragma unroll
            for (int j = 0; j < 4; j++) {
                float w = __uint_as_float(q[j].y);
                a0 = fmaf((float)r[j][0], w, a0);
                a1 = fmaf((float)r[j][1], w, a1);
            }
        }
        for (; e < e1; e++) {
            uint2 q = erec[e];
            float w = __uint_as_float(q.y);
            bf16x2 r = *(const bf16x2*)(hhi + (size_t)q.x * 128 + f);
            a0 = fmaf((float)r[0], w, a0);
            a1 = fmaf((float)r[1], w, a1);
        }

        a0 = fmaxf(a0, 0.f);
        a1 = fmaxf(a1, 0.f);
        bf16x2 oh, ol;
        oh[0] = (bf16)a0; ol[0] = (bf16)(a0 - (float)oh[0]);
        oh[1] = (bf16)a1; ol[1] = (bf16)(a1 - (float)oh[1]);
        *(bf16x2*)(ohi + nb) = oh;
        *(bf16x2*)(olo + nb) = ol;
    }
}

// ---------------- lin2 + log_softmax via MFMA (swapped operands) ----------------

__global__ __launch_bounds__(256) void lin2_mfma_lsm(
    const bf16* __restrict__ hhi, const bf16* __restrict__ hlo,
    const float* __restrict__ W, const float* __restrict__ bias,
    float* __restrict__ out, int n)
{
    const int lane = threadIdx.x & 63;
    const int l15  = lane & 15;
    const int lg   = lane >> 4;

    bf16x8 whi[3][4], wlo[3][4];
    #pragma unroll
    for (int t = 0; t < 3; t++) {
        int c = t * 16 + l15;
        bool valid = c < 40;
        #pragma unroll
        for (int ks = 0; ks < 4; ks++) {
            #pragma unroll
            for (int j = 0; j < 8; j++) {
                float wv = valid ? W[(ks * 32 + lg * 8 + j) * 40 + c] : 0.f;
                bf16 h = (bf16)wv;
                whi[t][ks][j] = h;
                wlo[t][ks][j] = (bf16)(wv - (float)h);
            }
        }
    }
    f32x4 bb[3];
    bool vstore[3];
    #pragma unroll
    for (int t = 0; t < 3; t++) {
        int c0 = t * 16 + lg * 4;
        vstore[t] = (c0 < 40);
        if (vstore[t]) bb[t] = *(const f32x4*)(bias + c0);
        else bb[t] = (f32x4){0.f, 0.f, 0.f, 0.f};
    }

    int wtile = (blockIdx.x * 256 + threadIdx.x) >> 6;
    int nwt   = (gridDim.x * 256) >> 6;
    int ntiles = (n + 15) >> 4;

    for (int rt = wtile; rt < ntiles; rt += nwt) {
        int arow = rt * 16 + l15;
        if (arow >= n) arow = n - 1;
        const bf16* pah = hhi + (size_t)arow * 128 + lg * 8;
        const bf16* pal = hlo + (size_t)arow * 128 + lg * 8;
        bf16x8 Ah[4], Al[4];
        #pragma unroll
        for (int ks = 0; ks < 4; ks++) {
            Ah[ks] = *(const bf16x8*)(pah + ks * 32);
            Al[ks] = *(const bf16x8*)(pal + ks * 32);
        }
        f32x4 acc[3];
        #pragma unroll
        for (int t = 0; t < 3; t++) {
            acc[t] = (f32x4){0.f, 0.f, 0.f, 0.f};
            #pragma unroll
            for (int ks = 0; ks < 4; ks++) {
                acc[t] = __builtin_amdgcn_mfma_f32_16x16x32_bf16(whi[t][ks], Al[ks], acc[t], 0, 0, 0);
                acc[t] = __builtin_amdgcn_mfma_f32_16x16x32_bf16(wlo[t][ks], Ah[ks], acc[t], 0, 0, 0);
                acc[t] = __builtin_amdgcn_mfma_f32_16x16x32_bf16(whi[t][ks], Ah[ks], acc[t], 0, 0, 0);
            }
        }
        float m = -INFINITY;
        #pragma unroll
        for (int t = 0; t < 3; t++) {
            if (vstore[t]) {
                #pragma unroll
                for (int r = 0; r < 4; r++) m = fmaxf(m, acc[t][r] + bb[t][r]);
            }
        }
        m = fmaxf(m, __shfl_xor(m, 16, 64));
        m = fmaxf(m, __shfl_xor(m, 32, 64));
        float s = 0.f;
        #pragma unroll
        for (int t = 0; t < 3; t++) {
            if (vstore[t]) {
                #pragma unroll
                for (int r = 0; r < 4; r++) s += __expf(acc[t][r] + bb[t][r] - m);
            }
        }
        s += __shfl_xor(s, 16, 64);
        s += __shfl_xor(s, 32, 64);
        float ls = __logf(s) + m;

        int node = rt * 16 + l15;
        if (node < n) {
            #pragma unroll
            for (int t = 0; t < 3; t++) {
                if (vstore[t]) {
                    f32x4 o;
                    #pragma unroll
                    for (int r = 0; r < 4; r++) o[r] = acc[t][r] + bb[t][r] - ls;
                    *(f32x4*)(out + (size_t)node * 40 + t * 16 + lg * 4) = o;
                }
            }
        }
    }
}

// ---------------- launch ----------------

static inline size_t align256(size_t x) { return (x + 255) & ~(size_t)255; }

extern "C" void kernel_launch(void* const* d_in, const int* in_sizes, int n_in,
                              void* d_out, int out_size, void* d_ws, size_t ws_size,
                              hipStream_t stream)
{
    const float* x   = (const float*)d_in[0];
    const int*   ei  = (const int*)d_in[1];
    const float* W1  = (const float*)d_in[2];  const float* b1  = (const float*)d_in[3];
    const float* W2  = (const float*)d_in[4];  const float* b2  = (const float*)d_in[5];
    const float* W3  = (const float*)d_in[6];  const float* b3  = (const float*)d_in[7];
    const float* l1w = (const float*)d_in[8];  const float* l1b = (const float*)d_in[9];
    const float* l2w = (const float*)d_in[10]; const float* l2b = (const float*)d_in[11];

    const int N = in_sizes[0] / 128;
    const int E = in_sizes[1] / 2;
    const int* src = ei;
    const int* dst = ei + E;

    char* wsb = (char*)d_ws;
    size_t o = 0;
    int*   deg   = (int*)(wsb + o);   o = align256(o + (size_t)N * 4);        // reused as cursor
    int*   off   = (int*)(wsb + o);   o = align256(o + (size_t)(N + 1) * 4);
    int*   bsum  = (int*)(wsb + o);   o = align256(o + (size_t)4096 * 4);
    int*   bcur  = (int*)(wsb + o);   o = align256(o + (size_t)512 * 4);
    uint2* erec  = (uint2*)(wsb + o); o = align256(o + (size_t)E * 8);
    float* dinv  = (float*)(wsb + o); o = align256(o + (size_t)N * 4);
    bf16*  ahi   = (bf16*)(wsb + o);  o = align256(o + (size_t)N * 128 * 2);
    bf16*  alo   = (bf16*)(wsb + o);  o = align256(o + (size_t)N * 128 * 2);
    bf16*  hhi   = (bf16*)(wsb + o);  o = align256(o + (size_t)N * 128 * 2);
    bf16*  hlo   = (bf16*)(wsb + o);  o = align256(o + (size_t)N * 128 * 2);

    uint2* ebuf = (uint2*)hhi;   // dead until gemm1; 12.8MB < 25.6MB region

    float* outp = (float*)d_out;
    const int nb   = (N + SCHUNK - 1) / SCHUNK;
    const int nbk  = (N + 255) >> BSH2;                 // 391 buckets
    const int npart = (E + PCH - 1) / PCH;              // 196 chunks

    // ---- CSR build: count, scan, partition, LDS counting sort ----
    zero_i32<<<(N + 255) / 256, 256, 0, stream>>>(deg, N);
    zero_i32<<<2, 256, 0, stream>>>(bcur, 512);
    count_deg<<<2048, 256, 0, stream>>>(dst, deg, E);
    finalize_dinv<<<(N + 255) / 256, 256, 0, stream>>>(deg, dinv, N);
    scan_p1<<<nb, 256, 0, stream>>>(deg, bsum, N);
    scan_p2<<<1, 64, 0, stream>>>(bsum, off, nb, N);
    scan_p3<<<nb, 256, 0, stream>>>(deg, bsum, off, deg /*cursor*/, N);
    partition_edges<<<npart, 256, 0, stream>>>(src, dst, off, bcur, ebuf, E, N, nbk);
    fill_sort<<<nbk, 256, 0, stream>>>(ebuf, off, dinv, deg /*cursor*/, erec, N, nbk);

    // ---- layer 1: gemm directly from fp32 x (split fused in-register) ----
    gemm_mfma_x<<<1024, 256, 0, stream>>>(x, W1, hhi, hlo, N);
    gather_agg_split<<<4096, 256, 0, stream>>>(hhi, hlo, erec, off, dinv, b1, ahi, alo, N);

    // ---- layer 2 ----
    gemm_mfma<<<1024, 256, 0, stream>>>(ahi, alo, W2, nullptr, hhi, hlo, N, 0);
    gather_agg_split<<<4096, 256, 0, stream>>>(hhi, hlo, erec, off, dinv, b2, ahi, alo, N);

    // ---- layer 3 ----
    gemm_mfma<<<1024, 256, 0, stream>>>(ahi, alo, W3, nullptr, hhi, hlo, N, 0);
    gather_agg_split<<<4096, 256, 0, stream>>>(hhi, hlo, erec, off, dinv, b3, ahi, alo, N);

    // ---- lin1 (+bias+relu) -> split bf16 ----
    gemm_mfma<<<1024, 256, 0, stream>>>(ahi, alo, l1w, l1b, hhi, hlo, N, 1);

    // ---- lin2 + log_softmax (MFMA, swapped) ----
    lin2_mfma_lsm<<<512, 256, 0, stream>>>(hhi, hlo, l2w, l2b, outp, N);
}